// Round 2
// baseline (566.623 us; speedup 1.0000x reference)
//
#include <hip/hip_runtime.h>
#include <math.h>

#define N_ROWS 16384
#define DMODEL 1024
#define DFF    4096

typedef _Float16 f16;
typedef __attribute__((ext_vector_type(4))) _Float16 f16x4;
typedef __attribute__((ext_vector_type(8))) _Float16 f16x8;
typedef __attribute__((ext_vector_type(4))) float f32x4;

__device__ inline void async_ld16(const f16* g, f16* l) {
  __builtin_amdgcn_global_load_lds(
      (__attribute__((address_space(1))) void*)(g),
      (__attribute__((address_space(3))) void*)(l),
      16, 0, 0);
}

// fp32 -> fp16 cast, 8 elems/thread, n divisible by 2048
__global__ void cast_to_f16(const float* __restrict__ src, f16* __restrict__ dst, int n) {
  int i = (blockIdx.x * blockDim.x + threadIdx.x) * 8;
  if (i >= n) return;
  float4 v0 = ((const float4*)(src + i))[0];
  float4 v1 = ((const float4*)(src + i))[1];
  f16x8 h = { (f16)v0.x, (f16)v0.y, (f16)v0.z, (f16)v0.w,
              (f16)v1.x, (f16)v1.y, (f16)v1.z, (f16)v1.w };
  *(f16x8*)(dst + i) = h;
}

__global__ void zero_f32(float* __restrict__ p, int n) {
  int i = blockIdx.x * blockDim.x + threadIdx.x;
  if (i < n) p[i] = 0.0f;
}

__global__ void sigmoid_f32(const float* __restrict__ pre, float* __restrict__ out, int n) {
  int i = blockIdx.x * blockDim.x + threadIdx.x;
  if (i < n) out[i] = 1.0f / (1.0f + expf(-pre[i]));
}

// ---------------------------------------------------------------------------
// Shared GEMM body pieces. LDS layout uses an XOR swizzle on the 16B chunk
// slot: global chunk c of row r is stored at slot (c ^ ((r>>2)&3)).
// Writer side: LDS slot is forced to tid*16B by global_load_lds, so thread
// tid (row=tid>>2, slot p=tid&3) FETCHES global chunk c = p ^ ((tid>>4)&3).
// Reader side: chunk c=lane>>4 of row (..+fr) lives at slot c ^ (fr>>2) —
// loop-invariant, since (wm+i*16) is a multiple of 16. Spreads the 16
// same-chunk lanes across all 8 bank-groups (2-way = free, m136) instead of
// 2 groups (8-way = 2.94x).
// ---------------------------------------------------------------------------

// C[M,Nc] = tanh(A[M,K] @ B[Nc,K]^T + bias) -> f16, fp32 acc. (GEMM1)
template <int K>
__global__ __launch_bounds__(256, 3)
void gemm_bt_tanh(const f16* __restrict__ A, const f16* __restrict__ B,
                  const float* __restrict__ bias, f16* __restrict__ C, int Nc) {
  __shared__ __align__(16) f16 As[128 * 32];
  __shared__ __align__(16) f16 Bs[128 * 32];

  const int tid  = threadIdx.x;
  const int lane = tid & 63;
  const int wave = tid >> 6;
  const size_t row0 = (size_t)blockIdx.x * 128;
  const size_t col0 = (size_t)blockIdx.y * 128;
  const int wm = (wave >> 1) * 64;
  const int wn = (wave & 1) * 64;
  const int fr = lane & 15;
  const int swz = (((lane >> 4) ^ (fr >> 2)) * 8);  // swizzled chunk offset (elems)

  const int srow   = tid >> 2;
  const int schunk = (((tid & 3) ^ ((tid >> 4) & 3)) * 8);  // swizzled global chunk
  const f16* Ap = A + (row0 + srow) * (size_t)K + schunk;
  const f16* Bp = B + (col0 + srow) * (size_t)K + schunk;
  f16* Asd = As + tid * 8;
  f16* Bsd = Bs + tid * 8;

  f32x4 acc[4][4] = {};

  for (int k0 = 0; k0 < K; k0 += 32) {
    __syncthreads();
    async_ld16(Ap + k0, Asd);
    async_ld16(Ap + (size_t)64 * K + k0, Asd + 2048);
    async_ld16(Bp + k0, Bsd);
    async_ld16(Bp + (size_t)64 * K + k0, Bsd + 2048);
    __syncthreads();

    f16x8 af[4], bf[4];
#pragma unroll
    for (int i = 0; i < 4; ++i) {
      af[i] = *(const f16x8*)(As + (wm + i * 16 + fr) * 32 + swz);
      bf[i] = *(const f16x8*)(Bs + (wn + i * 16 + fr) * 32 + swz);
    }
#pragma unroll
    for (int i = 0; i < 4; ++i)
#pragma unroll
      for (int j = 0; j < 4; ++j)
        acc[i][j] = __builtin_amdgcn_mfma_f32_16x16x32_f16(af[i], bf[j], acc[i][j], 0, 0, 0);
  }

  // C/D map: col=lane&15, row=(lane>>4)*4+reg [m89-verified]
  const int erow = wm + (lane >> 4) * 4;
  const int ecol = wn + fr;
#pragma unroll
  for (int i = 0; i < 4; ++i) {
#pragma unroll
    for (int j = 0; j < 4; ++j) {
      size_t gcol = col0 + ecol + j * 16;
      float b = bias[gcol];
#pragma unroll
      for (int r = 0; r < 4; ++r) {
        size_t grow = row0 + erow + i * 16 + r;
        C[grow * (size_t)Nc + gcol] = (f16)tanhf(acc[i][j][r] + b);
      }
    }
  }
}

// GEMM2 fused: wx = tanh(A@B^T + bias); pre[row] += sum_col wx*batch (atomics).
// No wx materialization.
template <int K>
__global__ __launch_bounds__(256, 3)
void gemm_bt_tanh_dot(const f16* __restrict__ A, const f16* __restrict__ B,
                      const float* __restrict__ bias,
                      const float* __restrict__ batch,  // [N_ROWS, DMODEL] fp32
                      float* __restrict__ pre) {
  __shared__ __align__(16) f16 As[128 * 32];
  __shared__ __align__(16) f16 Bs[128 * 32];

  const int tid  = threadIdx.x;
  const int lane = tid & 63;
  const int wave = tid >> 6;
  const size_t row0 = (size_t)blockIdx.x * 128;
  const size_t col0 = (size_t)blockIdx.y * 128;
  const int wm = (wave >> 1) * 64;
  const int wn = (wave & 1) * 64;
  const int fr = lane & 15;
  const int swz = (((lane >> 4) ^ (fr >> 2)) * 8);

  const int srow   = tid >> 2;
  const int schunk = (((tid & 3) ^ ((tid >> 4) & 3)) * 8);
  const f16* Ap = A + (row0 + srow) * (size_t)K + schunk;
  const f16* Bp = B + (col0 + srow) * (size_t)K + schunk;
  f16* Asd = As + tid * 8;
  f16* Bsd = Bs + tid * 8;

  f32x4 acc[4][4] = {};

  for (int k0 = 0; k0 < K; k0 += 32) {
    __syncthreads();
    async_ld16(Ap + k0, Asd);
    async_ld16(Ap + (size_t)64 * K + k0, Asd + 2048);
    async_ld16(Bp + k0, Bsd);
    async_ld16(Bp + (size_t)64 * K + k0, Bsd + 2048);
    __syncthreads();

    f16x8 af[4], bf[4];
#pragma unroll
    for (int i = 0; i < 4; ++i) {
      af[i] = *(const f16x8*)(As + (wm + i * 16 + fr) * 32 + swz);
      bf[i] = *(const f16x8*)(Bs + (wn + i * 16 + fr) * 32 + swz);
    }
#pragma unroll
    for (int i = 0; i < 4; ++i)
#pragma unroll
      for (int j = 0; j < 4; ++j)
        acc[i][j] = __builtin_amdgcn_mfma_f32_16x16x32_f16(af[i], bf[j], acc[i][j], 0, 0, 0);
  }

  // Fused epilogue: tanh, multiply by batch, reduce over cols, atomicAdd.
  const int erow = wm + (lane >> 4) * 4;
  const int ecol = wn + fr;
  float psum[4][4] = {};  // [i][r]
#pragma unroll
  for (int j = 0; j < 4; ++j) {
    size_t gcol = col0 + ecol + j * 16;
    float b = bias[gcol];
#pragma unroll
    for (int i = 0; i < 4; ++i) {
#pragma unroll
      for (int r = 0; r < 4; ++r) {
        size_t grow = row0 + erow + i * 16 + r;
        float w = tanhf(acc[i][j][r] + b);
        psum[i][r] += w * batch[grow * (size_t)DMODEL + gcol];
      }
    }
  }
  // reduce over the 16 col-lanes of each 16-lane group (rows differ by group)
#pragma unroll
  for (int i = 0; i < 4; ++i) {
#pragma unroll
    for (int r = 0; r < 4; ++r) {
      float s = psum[i][r];
      s += __shfl_xor(s, 1, 64);
      s += __shfl_xor(s, 2, 64);
      s += __shfl_xor(s, 4, 64);
      s += __shfl_xor(s, 8, 64);
      if (fr == 0) atomicAdd(&pre[row0 + erow + i * 16 + r], s);
    }
  }
}

extern "C" void kernel_launch(void* const* d_in, const int* in_sizes, int n_in,
                              void* d_out, int out_size, void* d_ws, size_t ws_size,
                              hipStream_t stream) {
  const float* batch = (const float*)d_in[0];
  const float* W1    = (const float*)d_in[1];
  const float* b1    = (const float*)d_in[2];
  const float* W2    = (const float*)d_in[3];
  const float* b2    = (const float*)d_in[4];
  float* out = (float*)d_out;

  char* ws = (char*)d_ws;
  f16* batch_h = (f16*)ws;  ws += (size_t)N_ROWS * DMODEL * sizeof(f16);  //  32 MB
  f16* W1_h    = (f16*)ws;  ws += (size_t)DFF * DMODEL * sizeof(f16);     //   8 MB
  f16* W2_h    = (f16*)ws;  ws += (size_t)DMODEL * DFF * sizeof(f16);     //   8 MB
  f16* inner_h = (f16*)ws;  ws += (size_t)N_ROWS * DFF * sizeof(f16);     // 128 MB
  float* pre   = (float*)ws; ws += (size_t)N_ROWS * sizeof(float);        //  64 KB

  const int nb = N_ROWS * DMODEL;
  const int nw = DFF * DMODEL;
  zero_f32<<<N_ROWS / 256, 256, 0, stream>>>(pre, N_ROWS);
  cast_to_f16<<<nb / 2048, 256, 0, stream>>>(batch, batch_h, nb);
  cast_to_f16<<<nw / 2048, 256, 0, stream>>>(W1, W1_h, nw);
  cast_to_f16<<<nw / 2048, 256, 0, stream>>>(W2, W2_h, nw);

  dim3 g1(N_ROWS / 128, DFF / 128);     // (128, 32)
  gemm_bt_tanh<DMODEL><<<g1, 256, 0, stream>>>(batch_h, W1_h, b1, inner_h, DFF);
  dim3 g2(N_ROWS / 128, DMODEL / 128);  // (128, 8)
  gemm_bt_tanh_dot<DFF><<<g2, 256, 0, stream>>>(inner_h, W2_h, b2, batch, pre);

  sigmoid_f32<<<N_ROWS / 256, 256, 0, stream>>>(pre, out, N_ROWS);
}

// Round 3
// 467.407 us; speedup vs baseline: 1.2123x; 1.2123x over previous
//
#include <hip/hip_runtime.h>
#include <math.h>

#define N_ROWS 16384
#define DMODEL 1024
#define DFF    4096

typedef _Float16 f16;
typedef __attribute__((ext_vector_type(4))) _Float16 f16x4;
typedef __attribute__((ext_vector_type(8))) _Float16 f16x8;
typedef __attribute__((ext_vector_type(4))) float f32x4;

__device__ inline void async_ld16(const f16* g, f16* l) {
  __builtin_amdgcn_global_load_lds(
      (__attribute__((address_space(1))) void*)(g),
      (__attribute__((address_space(3))) void*)(l),
      16, 0, 0);
}

// tanh via hw v_exp_f32: ~5 VALU ops vs libm tanhf's branchy ~40.
// Saturates correctly: x>>0 -> exp=inf -> 1-0=1; x<<0 -> exp=0 -> -1.
__device__ inline float fast_tanh(float x) {
  float t = __expf(2.0f * x);
  return 1.0f - 2.0f / (t + 1.0f);
}

// fp32 -> fp16 cast, 8 elems/thread, n divisible by 2048
__global__ void cast_to_f16(const float* __restrict__ src, f16* __restrict__ dst, int n) {
  int i = (blockIdx.x * blockDim.x + threadIdx.x) * 8;
  if (i >= n) return;
  float4 v0 = ((const float4*)(src + i))[0];
  float4 v1 = ((const float4*)(src + i))[1];
  f16x8 h = { (f16)v0.x, (f16)v0.y, (f16)v0.z, (f16)v0.w,
              (f16)v1.x, (f16)v1.y, (f16)v1.z, (f16)v1.w };
  *(f16x8*)(dst + i) = h;
}

// C[M,Nc] = tanh(A[M,K] @ B[Nc,K]^T + bias) -> f16, fp32 acc.
// m97 structure, BK=64 staged as two [128][32] half-tiles per operand:
// one barrier-pair covers 2 MFMA sub-steps (half the vmcnt(0) drains of BK=32),
// while keeping the 64B LDS row stride whose behavior is already calibrated.
// LDS 32KB -> still 3 blocks/CU.
template <int K>
__global__ __launch_bounds__(256, 3)
void gemm_bt_tanh(const f16* __restrict__ A, const f16* __restrict__ B,
                  const float* __restrict__ bias, f16* __restrict__ C, int Nc) {
  __shared__ __align__(16) f16 As[2 * 128 * 32];
  __shared__ __align__(16) f16 Bs[2 * 128 * 32];

  const int tid  = threadIdx.x;
  const int lane = tid & 63;
  const int wave = tid >> 6;
  const size_t row0 = (size_t)blockIdx.x * 128;
  const size_t col0 = (size_t)blockIdx.y * 128;
  const int wm = (wave >> 1) * 64;
  const int wn = (wave & 1) * 64;
  const int fr = lane & 15;
  const int fk = (lane >> 4) * 8;

  // Staging: 4 16B loads per operand per thread. Load l covers half-tile
  // h=l>>1 (k 0..31 vs 32..63); slot within half sp = (l&1)*256+tid;
  // row = sp>>2, k-chunk = h*4 + (sp&3). LDS dest = half-base + sp*16B
  // (wave-uniform base + lane-contiguous, as global_load_lds requires).
  const f16* Ag[4]; const f16* Bg[4]; f16* Asd[4]; f16* Bsd[4];
#pragma unroll
  for (int l = 0; l < 4; ++l) {
    const int sp  = (l & 1) * 256 + tid;
    const int row = sp >> 2;
    const int kch = (l >> 1) * 4 + (sp & 3);
    Ag[l]  = A + (row0 + row) * (size_t)K + kch * 8;
    Bg[l]  = B + (col0 + row) * (size_t)K + kch * 8;
    Asd[l] = As + (l >> 1) * 4096 + sp * 8;
    Bsd[l] = Bs + (l >> 1) * 4096 + sp * 8;
  }

  f32x4 acc[4][4] = {};

  for (int k0 = 0; k0 < K; k0 += 64) {
    __syncthreads();
#pragma unroll
    for (int l = 0; l < 4; ++l) async_ld16(Ag[l] + k0, Asd[l]);
#pragma unroll
    for (int l = 0; l < 4; ++l) async_ld16(Bg[l] + k0, Bsd[l]);
    __syncthreads();

#pragma unroll
    for (int s = 0; s < 2; ++s) {
      f16x8 af[4], bf[4];
#pragma unroll
      for (int i = 0; i < 4; ++i) {
        af[i] = *(const f16x8*)(As + s * 4096 + (wm + i * 16 + fr) * 32 + fk);
        bf[i] = *(const f16x8*)(Bs + s * 4096 + (wn + i * 16 + fr) * 32 + fk);
      }
#pragma unroll
      for (int i = 0; i < 4; ++i)
#pragma unroll
        for (int j = 0; j < 4; ++j)
          acc[i][j] = __builtin_amdgcn_mfma_f32_16x16x32_f16(af[i], bf[j], acc[i][j], 0, 0, 0);
    }
  }

  // C/D map: col=lane&15, row=(lane>>4)*4+reg [m89-verified]
  const int erow = wm + (lane >> 4) * 4;
  const int ecol = wn + fr;
#pragma unroll
  for (int i = 0; i < 4; ++i) {
#pragma unroll
    for (int j = 0; j < 4; ++j) {
      size_t gcol = col0 + ecol + j * 16;
      float b = bias[gcol];
#pragma unroll
      for (int r = 0; r < 4; ++r) {
        size_t grow = row0 + erow + i * 16 + r;
        C[grow * (size_t)Nc + gcol] = (f16)fast_tanh(acc[i][j][r] + b);
      }
    }
  }
}

// out[row] = sigmoid(sum_k wx[row][k] * batch[row][k]); 256 thr/row, fp32 acc
__global__ void rowdot_sigmoid(const f16* __restrict__ wx, const float* __restrict__ batch,
                               float* __restrict__ out) {
  const int row = blockIdx.x;
  const int t = threadIdx.x;
  const f16* wr = wx + (size_t)row * DMODEL + t * 4;
  const float* br = batch + (size_t)row * DMODEL + t * 4;
  f16x4 h = *(const f16x4*)wr;
  float4 b4 = *(const float4*)br;
  float s = (float)h[0] * b4.x + (float)h[1] * b4.y + (float)h[2] * b4.z + (float)h[3] * b4.w;
#pragma unroll
  for (int off = 32; off > 0; off >>= 1) s += __shfl_down(s, off, 64);
  __shared__ float partial[4];
  if ((t & 63) == 0) partial[t >> 6] = s;
  __syncthreads();
  if (t == 0) {
    float tot = partial[0] + partial[1] + partial[2] + partial[3];
    out[row] = 1.0f / (1.0f + __expf(-tot));
  }
}

extern "C" void kernel_launch(void* const* d_in, const int* in_sizes, int n_in,
                              void* d_out, int out_size, void* d_ws, size_t ws_size,
                              hipStream_t stream) {
  const float* batch = (const float*)d_in[0];
  const float* W1    = (const float*)d_in[1];
  const float* b1    = (const float*)d_in[2];
  const float* W2    = (const float*)d_in[3];
  const float* b2    = (const float*)d_in[4];
  float* out = (float*)d_out;

  char* ws = (char*)d_ws;
  f16* batch_h = (f16*)ws;  ws += (size_t)N_ROWS * DMODEL * sizeof(f16);  //  32 MB
  f16* W1_h    = (f16*)ws;  ws += (size_t)DFF * DMODEL * sizeof(f16);     //   8 MB
  f16* W2_h    = (f16*)ws;  ws += (size_t)DMODEL * DFF * sizeof(f16);     //   8 MB
  f16* inner_h = (f16*)ws;  ws += (size_t)N_ROWS * DFF * sizeof(f16);     // 128 MB
  f16* wx_h    = (f16*)ws;  ws += (size_t)N_ROWS * DMODEL * sizeof(f16);  //  32 MB

  const int nb = N_ROWS * DMODEL;
  const int nw = DFF * DMODEL;
  cast_to_f16<<<nb / 2048, 256, 0, stream>>>(batch, batch_h, nb);
  cast_to_f16<<<nw / 2048, 256, 0, stream>>>(W1, W1_h, nw);
  cast_to_f16<<<nw / 2048, 256, 0, stream>>>(W2, W2_h, nw);

  dim3 g1(N_ROWS / 128, DFF / 128);     // (128, 32)
  gemm_bt_tanh<DMODEL><<<g1, 256, 0, stream>>>(batch_h, W1_h, b1, inner_h, DFF);
  dim3 g2(N_ROWS / 128, DMODEL / 128);  // (128, 8)
  gemm_bt_tanh<DFF><<<g2, 256, 0, stream>>>(inner_h, W2_h, b2, wx_h, DMODEL);

  rowdot_sigmoid<<<N_ROWS, 256, 0, stream>>>(wx_h, batch, out);
}